// Round 1
// baseline (149.390 us; speedup 1.0000x reference)
//
#include <hip/hip_runtime.h>

#define H 224
#define W 224
#define HW (224 * 224)
#define CIN 3
#define OCH 64

#define BPX 32            // output px per block (one 32-px strip per wave-row)
#define BPY 4             // output rows per block (one per wave)
#define RRW 14            // raw tile rows  = BPY + 10 (5-halo each side: 2 conv + 3 gauss)
#define RCW 42            // raw tile cols  = BPX + 10
#define RST 44            // raw row stride (mult of 4 for b128 alignment)
#define MRW 8             // mod tile rows  = BPY + 4 (2-halo each side for 5x5 conv)
#define MCW 36            // mod tile cols  = BPX + 4
#define MST 40            // mod row stride (mult of 4)

typedef __attribute__((ext_vector_type(8))) short short8;
typedef __attribute__((ext_vector_type(4))) float f32x4;

// round-to-nearest-even f32->bf16, packed pair (lo in low 16, hi in high 16)
__device__ __forceinline__ unsigned f2bf_pk(float lo, float hi) {
    unsigned a = __float_as_uint(lo), b = __float_as_uint(hi);
    a = (a + 0x7FFFu + ((a >> 16) & 1u)) >> 16;
    b = (b + 0x7FFFu + ((b >> 16) & 1u)) & 0xFFFF0000u;
    return a | b;
}

// ---- prepass: weights (64,3,5,5) -> bf16 A-fragment layout ----
// A[m=oc][k'], k' = ks*32 + (ky*5+kx), zero-padded 25..31 per channel.
// Fragment (mt,ks): lane holds A[oc = mt*16+(lane&15)][k = q*8+j], j=0..7.
__global__ void make_wA(const float* __restrict__ w, uint4* __restrict__ wA) {
    int t = threadIdx.x;
    if (t >= 768) return;
    int lane = t & 63;
    int fi = t >> 6;            // 0..11 = mt*3+ks
    int mt = fi / 3, ks = fi - mt * 3;
    int q = lane >> 4;
    int oc = mt * 16 + (lane & 15);
    float v[8];
#pragma unroll
    for (int j = 0; j < 8; ++j) {
        int kk = q * 8 + j;
        v[j] = (kk < 25) ? w[oc * 75 + ks * 25 + kk] : 0.f;
    }
    uint4 r;
    r.x = f2bf_pk(v[0], v[1]);
    r.y = f2bf_pk(v[2], v[3]);
    r.z = f2bf_pk(v[4], v[5]);
    r.w = f2bf_pk(v[6], v[7]);
    wA[fi * 64 + lane] = r;
}

// ---- fused: stage raw tile -> modulate into LDS -> MFMA conv -> store ----
// Block: 256 threads = 4 waves. Output tile: BPY=4 rows x BPX=32 px x 64 oc.
// Wave wv handles row py0+wv, 32 px, all 64 oc (two 16-px MFMA column sets).
__global__ __launch_bounds__(256, 4) void fused(
    const uint4* __restrict__ wA, const float* __restrict__ in,
    const int* __restrict__ foa, float* __restrict__ out)
{
    __shared__ float s_raw[CIN][RRW][RST];   // 7.4 KB
    __shared__ float s_mod[CIN][MRW][MST];   // 3.8 KB

    int tid = threadIdx.x;
    int px0 = blockIdx.x * BPX;
    int py0 = blockIdx.y * BPY;
    int b = blockIdx.z;

    // ---- phase 1: stage raw tile (rows py0-5..py0+8, cols px0-5..px0+36) ----
    const float* src = in + (size_t)b * CIN * HW;
    for (int i = tid; i < CIN * RRW * RCW; i += 256) {
        int ch = i / (RRW * RCW);
        int rem = i - ch * (RRW * RCW);
        int rr = rem / RCW;
        int cc = rem - rr * RCW;
        int gr = py0 - 5 + rr, gc = px0 - 5 + cc;
        float v = 0.f;
        if ((unsigned)gr < H && (unsigned)gc < W) v = src[ch * HW + gr * W + gc];
        s_raw[ch][rr][cc] = v;
    }
    __syncthreads();

    // ---- phase 2: modulate. 3ch x 8 rows x 9 col-quads = 216 units ----
    float fr = (float)foa[2 * b + 0], fc = (float)foa[2 * b + 1];
    if (tid < 216) {
        int ch = tid / 72;
        int rem = tid - ch * 72;
        int r = rem / 9;              // 0..7  (mod-tile row)
        int qc = rem - r * 9;         // 0..8  (quad of 4 cols)
        int c0 = qc * 4;
        int gm_r = py0 - 2 + r;       // global modulated row

        float pw[4][7], inv[4], acc[4] = {0.f, 0.f, 0.f, 0.f};
#pragma unroll
        for (int o = 0; o < 4; ++o) {
            int gm_c = px0 - 2 + c0 + o;
            float dr = (float)gm_r - fr, dc = (float)gm_c - fc;
            float dist = sqrtf(dr * dr + dc * dc) * 3.1567268e-3f; // 1/sqrt(2*224^2)
            float sigma = 0.01f + 0.99f * dist;
            float ae = -0.5f / (sigma * sigma);
            float e1 = __expf(ae);
            float e2 = e1 * e1, e4 = e2 * e2, e9 = e4 * e4 * e1;
            pw[o][0] = e9; pw[o][1] = e4; pw[o][2] = e1; pw[o][3] = 1.f;
            pw[o][4] = e1; pw[o][5] = e4; pw[o][6] = e9;
            float S = 1.f + 2.f * (e1 + e4 + e9);
            inv[o] = 1.f / (S * S);
        }
#pragma unroll
        for (int ki = 0; ki < 7; ++ki) {
            const float* rp = &s_raw[ch][r + ki][c0];  // cols c0..c0+9, 16B-aligned
            float rv[10];
            *(f32x4*)&rv[0] = *(const f32x4*)&rp[0];
            *(f32x4*)&rv[4] = *(const f32x4*)&rp[4];
            rv[8] = rp[8]; rv[9] = rp[9];
#pragma unroll
            for (int o = 0; o < 4; ++o) {
                float rs = 0.f;
#pragma unroll
                for (int kj = 0; kj < 7; ++kj) rs += pw[o][kj] * rv[o + kj];
                acc[o] += pw[o][ki] * rs;
            }
        }
        float res[4];
#pragma unroll
        for (int o = 0; o < 4; ++o) {
            int gm_c = px0 - 2 + c0 + o;
            bool ok = ((unsigned)gm_r < H) && ((unsigned)gm_c < W);
            res[o] = ok ? acc[o] * inv[o] : 0.f;   // zero-pad outside image
        }
        *(f32x4*)&s_mod[ch][r][c0] = *(const f32x4*)res;
    }
    __syncthreads();

    // ---- phase 3: conv GEMM from LDS. wave wv -> row py0+wv, 32 px, 64 oc ----
    int lane = tid & 63;
    int wv = tid >> 6;
    int q = lane >> 4, li = lane & 15;
    int py = py0 + wv;

    // weight A-fragments (global, L1-hot, 192 B per lane)
    short8 aw[4][3];
#pragma unroll
    for (int mt = 0; mt < 4; ++mt)
#pragma unroll
        for (int ks = 0; ks < 3; ++ks) {
            union { uint4 u4; short8 s8; } cv;
            cv.u4 = wA[(mt * 3 + ks) * 64 + lane];
            aw[mt][ks] = cv.s8;
        }

    // per-lane LDS tap offsets (k = q*8+j; clamp padding taps to k=24: A weight=0)
    int moff[8];
#pragma unroll
    for (int j = 0; j < 8; ++j) {
        int kk = q * 8 + j;
        int kkc = kk > 24 ? 24 : kk;
        int ky = (kkc * 13) >> 6;         // kkc/5 for 0..24
        int kx = kkc - ky * 5;
        moff[j] = (wv + ky) * MST + kx;
    }

#pragma unroll
    for (int s = 0; s < 2; ++s) {
        int sc = s * 16;
        // B fragments: lane li -> pixel px0+sc+li, 8 taps per channel
        short8 bf[CIN];
#pragma unroll
        for (int ch = 0; ch < CIN; ++ch) {
            const float* mp = &s_mod[ch][0][sc + li];
            float v[8];
#pragma unroll
            for (int j = 0; j < 8; ++j) v[j] = mp[moff[j]];
            union { unsigned u[4]; short8 s8; } cv;
            cv.u[0] = f2bf_pk(v[0], v[1]);
            cv.u[1] = f2bf_pk(v[2], v[3]);
            cv.u[2] = f2bf_pk(v[4], v[5]);
            cv.u[3] = f2bf_pk(v[6], v[7]);
            bf[ch] = cv.s8;
        }

        f32x4 acc[4];
#pragma unroll
        for (int mt = 0; mt < 4; ++mt) acc[mt] = (f32x4){0.f, 0.f, 0.f, 0.f};
#pragma unroll
        for (int ch = 0; ch < CIN; ++ch)
#pragma unroll
            for (int mt = 0; mt < 4; ++mt)
                acc[mt] = __builtin_amdgcn_mfma_f32_16x16x32_bf16(
                    aw[mt][ch], bf[ch], acc[mt], 0, 0, 0);

        // store: oc = mt*16 + q*4 + r, px = px0+sc+li
#pragma unroll
        for (int mt = 0; mt < 4; ++mt) {
#pragma unroll
            for (int r = 0; r < 4; ++r) {
                int oc = mt * 16 + q * 4 + r;
                out[(size_t)(b * OCH + oc) * HW + (size_t)py * W + px0 + sc + li] = acc[mt][r];
            }
        }
    }
}

extern "C" void kernel_launch(void* const* d_in, const int* in_sizes, int n_in,
                              void* d_out, int out_size, void* d_ws, size_t ws_size,
                              hipStream_t stream) {
    const float* input  = (const float*)d_in[0];   // (8,3,224,224) fp32
    const int*   foa    = (const int*)d_in[1];     // (8,2) int32
    const float* weight = (const float*)d_in[2];   // (64,3,5,5) fp32
    float* outp = (float*)d_out;                   // (8,64,224,224) fp32

    uint4* wA = (uint4*)d_ws;                      // 12 KB

    make_wA<<<1, 768, 0, stream>>>(weight, wA);

    dim3 grid(W / BPX, H / BPY, 8);                // 7 x 56 x 8 = 3136 blocks
    fused<<<grid, 256, 0, stream>>>(wA, input, foa, outp);
}

// Round 2
// 130.295 us; speedup vs baseline: 1.1466x; 1.1466x over previous
//
#include <hip/hip_runtime.h>

#define H 224
#define W 224
#define HW (224 * 224)
#define CIN 3
#define OCH 64
#define PW 228            // padded plane row length (halfwords): 2-halo each side
#define PHW (228 * 228)   // 51984 cells per plane (bf16)

#define MT 32             // modulate tile: 32x32 px per block
#define RAWN 38           // 32 + 6 (3-halo each side for 7x7 gaussian)
#define RST 40            // raw LDS row stride (floats, mult of 4)

typedef __attribute__((ext_vector_type(8))) short short8;
typedef __attribute__((ext_vector_type(4))) float f32x4;

// round-to-nearest-even f32->bf16, packed pair (lo in low 16, hi in high 16)
__device__ __forceinline__ unsigned f2bf_pk(float lo, float hi) {
    unsigned a = __float_as_uint(lo), b = __float_as_uint(hi);
    a = (a + 0x7FFFu + ((a >> 16) & 1u)) >> 16;
    b = (b + 0x7FFFu + ((b >> 16) & 1u)) & 0xFFFF0000u;
    return a | b;
}

// ---- modulate: 32x32 px tile, quad-vectorized stencil, bf16 output ----
// Also folds in the weight->A-fragment prepass (block 0) and border zeroing
// (edge blocks), eliminating the make_wA and memset dispatches.
__global__ __launch_bounds__(256) void modulate(
    const float* __restrict__ in, const int* __restrict__ foa,
    const float* __restrict__ w, ushort* __restrict__ Pm,
    uint4* __restrict__ wA)
{
    __shared__ float s_raw[CIN][RAWN][RST];   // 18,240 B

    int tid = threadIdx.x;
    int bx = blockIdx.x, by = blockIdx.y, b = blockIdx.z;
    int tx0 = bx * MT, ty0 = by * MT;

    // ---- folded weight prepass: A[m=oc][k'=ks*32+(ky*5+kx)] bf16 fragments.
    // gemm dispatches after this kernel completes -> ordering safe.
    if ((bx | by | b) == 0) {
        for (int t = tid; t < 768; t += 256) {
            int lane = t & 63;
            int fi = t >> 6;            // 0..11 = mt*3+ks
            int mt = fi / 3, ks = fi - mt * 3;
            int q = lane >> 4;
            int oc = mt * 16 + (lane & 15);
            float v[8];
#pragma unroll
            for (int j = 0; j < 8; ++j) {
                int kk = q * 8 + j;
                v[j] = (kk < 25) ? w[oc * 75 + ks * 25 + kk] : 0.f;
            }
            uint4 r;
            r.x = f2bf_pk(v[0], v[1]);
            r.y = f2bf_pk(v[2], v[3]);
            r.z = f2bf_pk(v[4], v[5]);
            r.w = f2bf_pk(v[6], v[7]);
            wA[fi * 64 + lane] = r;
        }
    }

    // ---- stage raw tile (rows ty0-3..ty0+34, cols tx0-3..tx0+34) ----
    const float* src = in + (size_t)b * CIN * HW;
    for (int i = tid; i < CIN * RAWN * RAWN; i += 256) {
        int ch = i / (RAWN * RAWN);
        int rem = i - ch * (RAWN * RAWN);
        int rr = rem / RAWN;
        int cc = rem - rr * RAWN;
        int gr = ty0 - 3 + rr, gc = tx0 - 3 + cc;
        float v = 0.f;
        if ((unsigned)gr < H && (unsigned)gc < W) v = src[ch * HW + gr * W + gc];
        s_raw[ch][rr][cc] = v;
    }
    __syncthreads();

    // ---- compute: each thread owns a 4-px quad (row r, cols c0..c0+3) ----
    int r = tid >> 3, c0 = (tid & 7) << 2;
    int gr = ty0 + r;
    float fr = (float)foa[2 * b + 0], fc = (float)foa[2 * b + 1];

    float pw[4][7], inv[4];
#pragma unroll
    for (int o = 0; o < 4; ++o) {
        int gc = tx0 + c0 + o;
        float dr = (float)gr - fr, dc = (float)gc - fc;
        float dist = sqrtf(dr * dr + dc * dc) * 3.1567268e-3f; // 1/sqrt(2*224^2)
        float sigma = 0.01f + 0.99f * dist;
        float ae = -0.5f / (sigma * sigma);
        float e1 = __expf(ae);
        float e2 = e1 * e1, e4 = e2 * e2, e9 = e4 * e4 * e1;
        pw[o][0] = e9; pw[o][1] = e4; pw[o][2] = e1; pw[o][3] = 1.f;
        pw[o][4] = e1; pw[o][5] = e4; pw[o][6] = e9;
        float S = 1.f + 2.f * (e1 + e4 + e9);
        inv[o] = 1.f / (S * S);
    }

    ushort* plane = Pm + (size_t)b * CIN * PHW;
#pragma unroll
    for (int ch = 0; ch < CIN; ++ch) {
        float acc[4] = {0.f, 0.f, 0.f, 0.f};
#pragma unroll
        for (int ki = 0; ki < 7; ++ki) {
            const float* rp = &s_raw[ch][r + ki][c0];   // 16B-aligned
            float rv[10];
            *(float4*)&rv[0] = *(const float4*)rp;
            *(float4*)&rv[4] = *(const float4*)(rp + 4);
            *(float2*)&rv[8] = *(const float2*)(rp + 8);
#pragma unroll
            for (int o = 0; o < 4; ++o) {
                float rs = 0.f;
#pragma unroll
                for (int kj = 0; kj < 7; ++kj) rs += pw[o][kj] * rv[o + kj];
                acc[o] += pw[o][ki] * rs;
            }
        }
        // bf16 quad store (8B, aligned: Pm base chosen so idx%4==2 -> byte%8==0)
        uint2 st;
        st.x = f2bf_pk(acc[0] * inv[0], acc[1] * inv[1]);
        st.y = f2bf_pk(acc[2] * inv[2], acc[3] * inv[3]);
        *(uint2*)&plane[(size_t)ch * PHW + (size_t)(gr + 2) * PW + (tx0 + c0) + 2] = st;
    }

    // ---- border zeroing (cells disjoint from all interior writes) ----
    // cell(pr, c) lives at plane[ch*PHW + pr*PW + c + 2], c in [-2, 226)
    if (by == 0 || by == 6) {
        int pr0 = (by == 0) ? 0 : 226;                 // two rows pr0, pr0+1
        int cA = (bx == 0) ? -2 : tx0;
        int cB = (bx == 6) ? 226 : tx0 + MT;
        int n = cB - cA;                               // 32..36
        for (int i = tid; i < 2 * CIN * n; i += 256) {
            int ch = i / (2 * n);
            int rem = i - ch * 2 * n;
            int rr = rem / n;
            int c = cA + (rem - rr * n);
            plane[(size_t)ch * PHW + (size_t)(pr0 + rr) * PW + c + 2] = 0;
        }
    }
    if (bx == 0 || bx == 6) {
        int cb = (bx == 0) ? -2 : 224;                 // two cols cb, cb+1
        int rA = (by == 0) ? 2 : ty0 + 2;
        int rB = (by == 6) ? 226 : ty0 + 2 + MT;
        int n = rB - rA;                               // 32
        for (int i = tid; i < 2 * CIN * n; i += 256) {
            int ch = i / (2 * n);
            int rem = i - ch * 2 * n;
            int cc = rem / n;
            int pr = rA + (rem - cc * n);
            plane[(size_t)ch * PHW + (size_t)pr * PW + (cb + cc) + 2] = 0;
        }
    }
}

// ---- GEMM: barrier-free, LDS-free. One wave = 32 px x 64 oc. ----
__global__ __launch_bounds__(256, 4) void gemm(
    const uint4* __restrict__ wA, const ushort* __restrict__ Pm,
    float* __restrict__ out)
{
    int tid = threadIdx.x;
    int lane = tid & 63;
    int wv = tid >> 6;
    int q = lane >> 4, li = lane & 15;

    int px0 = blockIdx.x * 32;            // 7 chunks across the row
    int py = blockIdx.y * 4 + wv;         // 56 row groups x 4 waves
    int b = blockIdx.z;

    // weight A-fragments (L1-hot, 192 B per lane, amortized over 32 px)
    short8 aw[4][3];
#pragma unroll
    for (int mt = 0; mt < 4; ++mt)
#pragma unroll
        for (int ks = 0; ks < 3; ++ks) {
            union { uint4 u4; short8 s8; } cv;
            cv.u4 = wA[(mt * 3 + ks) * 64 + lane];
            aw[mt][ks] = cv.s8;
        }

    // per-lane gather offsets (k = q*8+j; clamp padding taps to k=24: weight=0)
    int ofs[8];
#pragma unroll
    for (int j = 0; j < 8; ++j) {
        int kk = q * 8 + j;
        int kkc = kk > 24 ? 24 : kk;
        int ky = (kkc * 13) >> 6;         // kkc/5 for 0..24
        int kx = kkc - ky * 5;
        ofs[j] = ky * PW + kx;
    }

#pragma unroll
    for (int s = 0; s < 2; ++s) {
        int px = px0 + s * 16 + li;
        // B fragments: bf16 taps loaded raw, assembled with or/shift (no cvt)
        short8 bf[CIN];
#pragma unroll
        for (int ch = 0; ch < CIN; ++ch) {
            const ushort* p = Pm + (size_t)(b * CIN + ch) * PHW + (size_t)py * PW + px;
            unsigned v[8];
#pragma unroll
            for (int j = 0; j < 8; ++j) v[j] = p[ofs[j]];
            union { unsigned u[4]; short8 s8; } cv;
            cv.u[0] = v[0] | (v[1] << 16);
            cv.u[1] = v[2] | (v[3] << 16);
            cv.u[2] = v[4] | (v[5] << 16);
            cv.u[3] = v[6] | (v[7] << 16);
            bf[ch] = cv.s8;
        }

        f32x4 acc[4];
#pragma unroll
        for (int mt = 0; mt < 4; ++mt) acc[mt] = (f32x4){0.f, 0.f, 0.f, 0.f};
#pragma unroll
        for (int ch = 0; ch < CIN; ++ch)
#pragma unroll
            for (int mt = 0; mt < 4; ++mt)
                acc[mt] = __builtin_amdgcn_mfma_f32_16x16x32_bf16(
                    aw[mt][ch], bf[ch], acc[mt], 0, 0, 0);

        // store: oc = mt*16 + q*4 + r, 64B segments per (q,r)
#pragma unroll
        for (int mt = 0; mt < 4; ++mt) {
#pragma unroll
            for (int r = 0; r < 4; ++r) {
                int oc = mt * 16 + q * 4 + r;
                out[(size_t)(b * OCH + oc) * HW + (size_t)py * W + px] = acc[mt][r];
            }
        }
    }
}

extern "C" void kernel_launch(void* const* d_in, const int* in_sizes, int n_in,
                              void* d_out, int out_size, void* d_ws, size_t ws_size,
                              hipStream_t stream) {
    const float* input  = (const float*)d_in[0];   // (8,3,224,224) fp32
    const int*   foa    = (const int*)d_in[1];     // (8,2) int32
    const float* weight = (const float*)d_in[2];   // (64,3,5,5) fp32
    float* outp = (float*)d_out;                   // (8,64,224,224) fp32

    uint4*  wA = (uint4*)d_ws;                     // 12,288 B
    // bf16 Pm base at +16380: (16380 % 8) == 4 makes the interior quad stores
    // (halfword index % 4 == 2) land on 8B-aligned addresses.
    ushort* Pm = (ushort*)((char*)d_ws + 16380);   // 24 planes x 51984 x 2B ~ 2.5 MB

    dim3 gridM(W / MT, H / MT, 8);      // 7 x 7 x 8 = 392 blocks
    modulate<<<gridM, 256, 0, stream>>>(input, foa, weight, Pm, wA);

    dim3 gridG(7, 56, 8);               // 32-px chunks x row-groups x batch
    gemm<<<gridG, 256, 0, stream>>>(wA, Pm, outp);
}

// Round 3
// 126.282 us; speedup vs baseline: 1.1830x; 1.0318x over previous
//
#include <hip/hip_runtime.h>

#define H 224
#define W 224
#define HW (224 * 224)
#define CIN 3
#define OCH 64

#define TS 32             // output tile: 32x32 px per block
#define MN 36             // modulated tile: 36x36 (2-halo for 5x5 conv)
#define MSTH 40           // s_mod row stride (halfwords, mult of 4)
#define RN 42             // raw tile: 42x42 (further 3-halo for 7x7 gaussian)
#define RST 44            // s_raw row stride (floats, mult of 4)

typedef __attribute__((ext_vector_type(8))) short short8;
typedef __attribute__((ext_vector_type(4))) float f32x4;

// round-to-nearest-even f32->bf16, packed pair (lo in low 16, hi in high 16)
__device__ __forceinline__ unsigned f2bf_pk(float lo, float hi) {
    unsigned a = __float_as_uint(lo), b = __float_as_uint(hi);
    a = (a + 0x7FFFu + ((a >> 16) & 1u)) >> 16;
    b = (b + 0x7FFFu + ((b >> 16) & 1u)) & 0xFFFF0000u;
    return a | b;
}

// ---- weight prepass: (64,3,5,5) -> bf16 A-fragments, SECTIONED K-layout ----
// 4 K-sections of 32:
//   S<3 : channel S, k = ky*8 + kx (ky=0..3 <-> lane q, kx=0..4 <-> j; j>=5 zero)
//   S=3 : ky=4 row of channel q (q=0..2; q=3 all zero), kx <-> j
// Fragment (mt,S): lane (q,li) holds A[oc=mt*16+li][k=q*8+j], j=0..7.
__global__ void make_wA(const float* __restrict__ w, uint4* __restrict__ wA) {
    int t = threadIdx.x;          // 1024 threads, exact
    int lane = t & 63;
    int fi = t >> 6;              // 0..15 = mt*4 + S
    int mt = fi >> 2, S = fi & 3;
    int q = lane >> 4;
    int oc = mt * 16 + (lane & 15);
    float v[8];
#pragma unroll
    for (int j = 0; j < 8; ++j) {
        float x = 0.f;
        if (j < 5) {
            if (S < 3) x = w[oc * 75 + S * 25 + q * 5 + j];
            else if (q < 3) x = w[oc * 75 + q * 25 + 20 + j];
        }
        v[j] = x;
    }
    uint4 r;
    r.x = f2bf_pk(v[0], v[1]);
    r.y = f2bf_pk(v[2], v[3]);
    r.z = f2bf_pk(v[4], v[5]);
    r.w = f2bf_pk(v[6], v[7]);
    wA[fi * 64 + lane] = r;
}

// ---- fused: stage raw -> modulate (LDS, bf16) -> sectioned MFMA conv ----
// Block = 32x32 output px, 4 waves; wave wv owns rows wv*8..wv*8+7, 64 oc.
__global__ __launch_bounds__(256, 2) void fused(
    const uint4* __restrict__ wA, const float* __restrict__ in,
    const int* __restrict__ foa, float* __restrict__ out)
{
    __shared__ float  s_raw[CIN][RN][RST];    // 22,176 B
    __shared__ ushort s_mod[CIN][MN][MSTH];   //  8,640 B

    int tid = threadIdx.x;
    int lane = tid & 63;
    int tx0 = blockIdx.x * TS, ty0 = blockIdx.y * TS, b = blockIdx.z;

    // prefetch weight fragments (16 KB table, L2-hot); hidden under staging
    short8 aw[4][4];
#pragma unroll
    for (int mt = 0; mt < 4; ++mt)
#pragma unroll
        for (int S = 0; S < 4; ++S) {
            union { uint4 u4; short8 s8; } cv;
            cv.u4 = wA[(mt * 4 + S) * 64 + lane];
            aw[mt][S] = cv.s8;
        }

    // ---- phase 1: stage raw tile (rows ty0-5..ty0+36, cols tx0-5..tx0+36) ----
    const float* src = in + (size_t)b * CIN * HW;
    for (int i = tid; i < CIN * RN * RN; i += 256) {
        int ch = i / (RN * RN);
        int rem = i - ch * (RN * RN);
        int rr = rem / RN;
        int cc = rem - rr * RN;
        int gr = ty0 - 5 + rr, gc = tx0 - 5 + cc;
        float v = 0.f;
        if ((unsigned)gr < H && (unsigned)gc < W) v = src[ch * HW + gr * W + gc];
        s_raw[ch][rr][cc] = v;
    }
    __syncthreads();

    // ---- phase 2: modulate 36x36x3 into s_mod (bf16). unit = ch-row-quad ----
    float fr = (float)foa[2 * b + 0], fc = (float)foa[2 * b + 1];
    for (int u = tid; u < CIN * MN * 9; u += 256) {       // 972 units
        int ch = u / (MN * 9);
        int rem = u - ch * (MN * 9);
        int rm = rem / 9;
        int qc = rem - rm * 9;
        int cm0 = qc * 4;
        int gr = ty0 - 2 + rm;

        float pw[4][7], inv[4];
#pragma unroll
        for (int o = 0; o < 4; ++o) {
            int gc = tx0 - 2 + cm0 + o;
            float dr = (float)gr - fr, dc = (float)gc - fc;
            float dist = sqrtf(dr * dr + dc * dc) * 3.1567268e-3f; // 1/sqrt(2*224^2)
            float sigma = 0.01f + 0.99f * dist;
            float ae = -0.5f / (sigma * sigma);
            float e1 = __expf(ae);
            float e2 = e1 * e1, e4 = e2 * e2, e9 = e4 * e4 * e1;
            pw[o][0] = e9; pw[o][1] = e4; pw[o][2] = e1; pw[o][3] = 1.f;
            pw[o][4] = e1; pw[o][5] = e4; pw[o][6] = e9;
            float S = 1.f + 2.f * (e1 + e4 + e9);
            inv[o] = 1.f / (S * S);
        }
        float acc[4] = {0.f, 0.f, 0.f, 0.f};
#pragma unroll
        for (int ki = 0; ki < 7; ++ki) {
            const float* rp = &s_raw[ch][rm + ki][cm0];   // 16B-aligned
            float rv[10];
            *(f32x4*)&rv[0] = *(const f32x4*)rp;
            *(f32x4*)&rv[4] = *(const f32x4*)(rp + 4);
            *(float2*)&rv[8] = *(const float2*)(rp + 8);
#pragma unroll
            for (int o = 0; o < 4; ++o) {
                float rs = 0.f;
#pragma unroll
                for (int kj = 0; kj < 7; ++kj) rs += pw[o][kj] * rv[o + kj];
                acc[o] += pw[o][ki] * rs;
            }
        }
        float res[4];
#pragma unroll
        for (int o = 0; o < 4; ++o) {
            int gc = tx0 - 2 + cm0 + o;
            bool ok = ((unsigned)gr < H) && ((unsigned)gc < W);
            res[o] = ok ? acc[o] * inv[o] : 0.f;          // zero-pad outside
        }
        uint2 st;
        st.x = f2bf_pk(res[0], res[1]);
        st.y = f2bf_pk(res[2], res[3]);
        *(uint2*)&s_mod[ch][rm][cm0] = st;                // 8B-aligned
    }
    __syncthreads();

    // ---- phase 3: sectioned MFMA conv from LDS ----
    int wv = tid >> 6;
    int q = lane >> 4, li = lane & 15;

#pragma unroll
    for (int r8 = 0; r8 < 8; ++r8) {
        int ro = wv * 8 + r8;
#pragma unroll
        for (int s = 0; s < 2; ++s) {
            int co = s * 16 + li;
            int cd = co >> 1;                 // dword offset of even-col base
            unsigned sel = (unsigned)(co & 1) * 16u;

            short8 bf[4];
#pragma unroll
            for (int S = 0; S < 4; ++S) {
                int ch = (S < 3) ? S : (q < 3 ? q : 2);
                int rm = (S < 3) ? (ro + q) : (ro + 4);
                const unsigned* p = (const unsigned*)&s_mod[ch][rm][0] + cd;
                unsigned u0 = p[0], u1 = p[1], u2 = p[2];
                // 5-tap window w[co..co+4]; j>=5 slots multiply A=0 (finite data)
                union { unsigned u[4]; short8 s8; } cv;
                cv.u[0] = __builtin_amdgcn_alignbit(u1, u0, sel);
                cv.u[1] = __builtin_amdgcn_alignbit(u2, u1, sel);
                cv.u[2] = u2 >> sel;
                cv.u[3] = 0;
                bf[S] = cv.s8;
            }

            f32x4 acc[4];
#pragma unroll
            for (int mt = 0; mt < 4; ++mt) acc[mt] = (f32x4){0.f, 0.f, 0.f, 0.f};
#pragma unroll
            for (int S = 0; S < 4; ++S)
#pragma unroll
                for (int mt = 0; mt < 4; ++mt)
                    acc[mt] = __builtin_amdgcn_mfma_f32_16x16x32_bf16(
                        aw[mt][S], bf[S], acc[mt], 0, 0, 0);

            int px = tx0 + co, py = ty0 + ro;
#pragma unroll
            for (int mt = 0; mt < 4; ++mt) {
#pragma unroll
                for (int r = 0; r < 4; ++r) {
                    int oc = mt * 16 + q * 4 + r;
                    out[(size_t)(b * OCH + oc) * HW + (size_t)py * W + px] = acc[mt][r];
                }
            }
        }
    }
}

extern "C" void kernel_launch(void* const* d_in, const int* in_sizes, int n_in,
                              void* d_out, int out_size, void* d_ws, size_t ws_size,
                              hipStream_t stream) {
    const float* input  = (const float*)d_in[0];   // (8,3,224,224) fp32
    const int*   foa    = (const int*)d_in[1];     // (8,2) int32
    const float* weight = (const float*)d_in[2];   // (64,3,5,5) fp32
    float* outp = (float*)d_out;                   // (8,64,224,224) fp32

    uint4* wA = (uint4*)d_ws;                      // 16 KB

    make_wA<<<1, 1024, 0, stream>>>(weight, wA);

    dim3 grid(W / TS, H / TS, 8);                  // 7 x 7 x 8 = 392 blocks
    fused<<<grid, 256, 0, stream>>>(wA, input, foa, outp);
}